// Round 10
// baseline (371.472 us; speedup 1.0000x reference)
//
#include <hip/hip_runtime.h>
#include <cstdint>
#include <cstddef>

// ---------- types / helpers ----------
typedef unsigned short bf16_t;
typedef __attribute__((ext_vector_type(8))) short bf16x8;   // 8 bf16 in 4 VGPRs (MFMA A/B frag)
typedef __attribute__((ext_vector_type(4))) float f32x4;    // MFMA C/D frag

__device__ __forceinline__ float bf2f(bf16_t b) {
  unsigned int u = ((unsigned int)b) << 16;
  return __builtin_bit_cast(float, u);
}
__device__ __forceinline__ bf16_t f2bf(float f) {
  unsigned int u = __builtin_bit_cast(unsigned int, f);
  u += 0x7fffu + ((u >> 16) & 1u);   // round-to-nearest-even
  return (bf16_t)(u >> 16);
}
__device__ __forceinline__ float exp2_hw(float x) {
  return __builtin_amdgcn_exp2f(x);   // v_exp_f32: D = 2^S0
}

// Problem constants
constexpr int SEQ = 2048, NE = 2560, NH = 32, HD = 80, OP = 7680;

// ---------- fused f32 -> bf16 convert (grid-stride, 2048 blocks - G11) ----------
__global__ void cvt3(const float* __restrict__ s0, const float* __restrict__ s1,
                     const float* __restrict__ s2, bf16_t* __restrict__ d0,
                     bf16_t* __restrict__ d1, bf16_t* __restrict__ d2)
{
  constexpr int N0 = SEQ * NE / 4, N1 = OP * NE / 4, N2 = NE * NE / 4;
  constexpr int TOT = N0 + N1 + N2;   // 7,864,320 float4 groups
  for (int t0 = blockIdx.x * 256 + threadIdx.x; t0 < TOT; t0 += 2048 * 256) {
    int t = t0;
    const float* s; bf16_t* d;
    if (t < N0)            { s = s0; d = d0; }
    else if (t < N0 + N1)  { s = s1; d = d1; t -= N0; }
    else                   { s = s2; d = d2; t -= N0 + N1; }
    float4 v = ((const float4*)s)[t];
    ushort4 o;
    o.x = f2bf(v.x); o.y = f2bf(v.y); o.z = f2bf(v.z); o.w = f2bf(v.w);
    ((ushort4*)d)[t] = o;
  }
}

// ---------- store helpers (GEMM output: bf16 or f32) ----------
__device__ __forceinline__ void store_out(bf16_t* p, float v) { *p = f2bf(v); }
__device__ __forceinline__ void store_out(float* p, float v)  { *p = v; }

// ============================================================================
// 256x256 GEMM (QKV): C[m,n] = sum_k A[m,k]*B[n,k] + bias[n]
// 8 waves (2M x 4N), BK=64, 2 K-tile LDS double buffer (128 KiB), T2 swizzle.
// ONE barrier per K-tile; operand ds_reads issued one phase ahead of use.
// (Best-measured QKV structure: ~87 us on fast containers, MfmaUtil ~38%.)
// ============================================================================
__global__ __launch_bounds__(512, 2) void gemm256_bt_bias(
    const bf16_t* __restrict__ A,    // [M, K] row-major bf16
    const bf16_t* __restrict__ B,    // [N, K] row-major bf16
    const float*  __restrict__ bias, // [N] f32
    bf16_t* __restrict__ C,          // [M, N] bf16
    int M, int N, int K)
{
  __shared__ bf16_t As[2][256 * 64];   // 32 KB per buffer
  __shared__ bf16_t Bs[2][256 * 64];

  const int tid  = threadIdx.x;
  const int lane = tid & 63;
  const int wave = tid >> 6;
  const int wm   = wave >> 2;    // 0..1  (M half)
  const int wn   = wave & 3;     // 0..3  (N quarter)
  const int lm   = lane & 15;
  const int quad = lane >> 4;
  const int m0 = blockIdx.y * 256;
  const int n0 = blockIdx.x * 256;
  const int NT = K / 64;

  // ---- staging per-lane constants (inverse-swizzled global source) ----
  const int srow = lane >> 3;                      // 0..7
  const int scol = ((lane & 7) ^ srow) * 8;        // logical elem col for this lane's slot

  auto stage = [&](const bf16_t* __restrict__ P, int R0, int K0, int H, bf16_t* DST) {
#pragma unroll
    for (int cc = 0; cc < 2; ++cc) {
      const int seg = wave * 2 + cc;               // 0..15 (wave-uniform)
      const bf16_t* src = P + (size_t)(R0 + H * 128 + seg * 8 + srow) * K + K0 + scol;
      __builtin_amdgcn_global_load_lds(
          (const __attribute__((address_space(1))) unsigned int*)src,
          (__attribute__((address_space(3))) unsigned int*)(DST + H * 8192 + seg * 512),
          16, 0, 0);
    }
  };

  // ---- swizzled ds_read slot offsets (lane-constant) ----
  const int xk0 = ((0 + quad) ^ (lm & 7)) * 8;     // kk=0: logical slot quad
  const int xk1 = ((4 + quad) ^ (lm & 7)) * 8;     // kk=1: logical slot 4+quad

  const int AOFF = (wm * 128 + lm) * 64;           // + h*4096 + i*1024 + xk
  const int BOFF = (wn * 64  + lm) * 64;           // + j*1024 (+2048 for b23) + xk

  f32x4 acc[8][4];
#pragma unroll
  for (int i = 0; i < 8; ++i)
#pragma unroll
    for (int j = 0; j < 4; ++j)
      acc[i][j] = (f32x4){0.f, 0.f, 0.f, 0.f};

  // ---- prologue: stage tile0 (oldest 8) then tile1 (next 8) ----
  stage(A, m0, 0, 0, As[0]);  stage(A, m0, 0, 1, As[0]);
  stage(B, n0, 0, 0, Bs[0]);  stage(B, n0, 0, 1, Bs[0]);
  stage(A, m0, 64, 0, As[1]); stage(A, m0, 64, 1, As[1]);
  stage(B, n0, 64, 0, Bs[1]); stage(B, n0, 64, 1, Bs[1]);

  asm volatile("s_waitcnt vmcnt(8)" ::: "memory");   // tile0 staged
  __builtin_amdgcn_s_barrier();
  __builtin_amdgcn_sched_barrier(0);

  bf16x8 a[4][2], b01[2][2], b23[2][2];
  // pre-read: b01 = B(0)[n 0:32], a = A(0)[m 0:64]
#pragma unroll
  for (int j = 0; j < 2; ++j) {
    b01[j][0] = *(const bf16x8*)(&Bs[0][BOFF + j * 1024 + xk0]);
    b01[j][1] = *(const bf16x8*)(&Bs[0][BOFF + j * 1024 + xk1]);
  }
#pragma unroll
  for (int i = 0; i < 4; ++i) {
    a[i][0] = *(const bf16x8*)(&As[0][AOFF + i * 1024 + xk0]);
    a[i][1] = *(const bf16x8*)(&As[0][AOFF + i * 1024 + xk1]);
  }
  __builtin_amdgcn_sched_barrier(0);

  for (int t = 0; t < NT; ++t) {
    const int c = t & 1;
    const bf16_t* Ac = &As[c][0];
    const bf16_t* Bc = &Bs[c][0];
    const bf16_t* An = &As[c ^ 1][0];
    const bf16_t* Bn = &Bs[c ^ 1][0];

    // ===== ph0: acc[0..3][0..1] += a(A half0) x b01 =====
    __builtin_amdgcn_s_setprio(1);
#pragma unroll
    for (int kk = 0; kk < 2; ++kk)
#pragma unroll
      for (int i = 0; i < 2; ++i)
#pragma unroll
        for (int j = 0; j < 2; ++j)
          acc[i][j] = __builtin_amdgcn_mfma_f32_16x16x32_bf16(a[i][kk], b01[j][kk], acc[i][j], 0, 0, 0);
    __builtin_amdgcn_s_setprio(0);
    // issue b23 reads (dead regs; used in ph1)
#pragma unroll
    for (int j = 0; j < 2; ++j) {
      b23[j][0] = *(const bf16x8*)(Bc + BOFF + (2 + j) * 1024 + xk0);
      b23[j][1] = *(const bf16x8*)(Bc + BOFF + (2 + j) * 1024 + xk1);
    }
    __builtin_amdgcn_sched_barrier(0);
    __builtin_amdgcn_s_setprio(1);
#pragma unroll
    for (int kk = 0; kk < 2; ++kk)
#pragma unroll
      for (int i = 2; i < 4; ++i)
#pragma unroll
        for (int j = 0; j < 2; ++j)
          acc[i][j] = __builtin_amdgcn_mfma_f32_16x16x32_bf16(a[i][kk], b01[j][kk], acc[i][j], 0, 0, 0);
    __builtin_amdgcn_s_setprio(0);
    __builtin_amdgcn_sched_barrier(0);

    // ===== ph1: acc[0..3][2..3] += a(A half0) x b23 =====
    __builtin_amdgcn_s_setprio(1);
#pragma unroll
    for (int kk = 0; kk < 2; ++kk)
#pragma unroll
      for (int i = 0; i < 4; ++i)
#pragma unroll
        for (int j = 0; j < 2; ++j)
          acc[i][2 + j] = __builtin_amdgcn_mfma_f32_16x16x32_bf16(a[i][kk], b23[j][kk], acc[i][2 + j], 0, 0, 0);
    __builtin_amdgcn_s_setprio(0);
    // issue a = A half1 reads (a dead after ph1; used in ph2)
#pragma unroll
    for (int i = 0; i < 4; ++i) {
      a[i][0] = *(const bf16x8*)(Ac + AOFF + 4096 + i * 1024 + xk0);
      a[i][1] = *(const bf16x8*)(Ac + AOFF + 4096 + i * 1024 + xk1);
    }
    __builtin_amdgcn_sched_barrier(0);

    // ===== ph2: acc[4..7][0..1] += a(A half1) x b01 =====
    __builtin_amdgcn_s_setprio(1);
#pragma unroll
    for (int kk = 0; kk < 2; ++kk)
#pragma unroll
      for (int i = 0; i < 4; ++i)
#pragma unroll
        for (int j = 0; j < 2; ++j)
          acc[4 + i][j] = __builtin_amdgcn_mfma_f32_16x16x32_bf16(a[i][kk], b01[j][kk], acc[4 + i][j], 0, 0, 0);
    __builtin_amdgcn_s_setprio(0);
    __builtin_amdgcn_sched_barrier(0);

    // ---- the ONE sync point per K-tile ----
    asm volatile("s_waitcnt lgkmcnt(0)" ::: "memory");   // ~free: all reads consumed
    asm volatile("s_waitcnt vmcnt(0)"  ::: "memory");    // t+1 staging (issued 4 phases ago)
    __builtin_amdgcn_s_barrier();
    __builtin_amdgcn_sched_barrier(0);
    // issue b01 = B(t+1)[n 0:32] from next buffer (b01 dead)
    if (t + 1 < NT) {
#pragma unroll
      for (int j = 0; j < 2; ++j) {
        b01[j][0] = *(const bf16x8*)(Bn + BOFF + j * 1024 + xk0);
        b01[j][1] = *(const bf16x8*)(Bn + BOFF + j * 1024 + xk1);
      }
    }
    __builtin_amdgcn_sched_barrier(0);

    // ===== ph3: acc[4..7][2..3] += a(A half1) x b23 =====
    __builtin_amdgcn_s_setprio(1);
#pragma unroll
    for (int kk = 0; kk < 2; ++kk)
#pragma unroll
      for (int i = 0; i < 4; ++i)
#pragma unroll
        for (int j = 0; j < 2; ++j)
          acc[4 + i][2 + j] = __builtin_amdgcn_mfma_f32_16x16x32_bf16(a[i][kk], b23[j][kk], acc[4 + i][2 + j], 0, 0, 0);
    __builtin_amdgcn_s_setprio(0);
    // stage tile t+2 into buffer c (all buffer-c reads drained before the barrier)
    if (t + 2 < NT) {
      stage(B, n0, (t + 2) * 64, 0, (bf16_t*)Bs[c]);
      stage(B, n0, (t + 2) * 64, 1, (bf16_t*)Bs[c]);
      stage(A, m0, (t + 2) * 64, 0, (bf16_t*)As[c]);
      stage(A, m0, (t + 2) * 64, 1, (bf16_t*)As[c]);
    }
    // issue a = A(t+1)[m 0:64] from next buffer (a dead after ph3)
    if (t + 1 < NT) {
#pragma unroll
      for (int i = 0; i < 4; ++i) {
        a[i][0] = *(const bf16x8*)(An + AOFF + i * 1024 + xk0);
        a[i][1] = *(const bf16x8*)(An + AOFF + i * 1024 + xk1);
      }
    }
    __builtin_amdgcn_sched_barrier(0);
  }

  // ---- epilogue: D mapping col=lane&15, row=quad*4+reg ----
#pragma unroll
  for (int i = 0; i < 8; ++i) {
#pragma unroll
    for (int j = 0; j < 4; ++j) {
      const int n = n0 + wn * 64 + j * 16 + lm;
      const float bv = bias ? bias[n] : 0.f;
#pragma unroll
      for (int r = 0; r < 4; ++r) {
        const int m = m0 + wm * 128 + i * 16 + quad * 4 + r;
        C[(size_t)m * N + n] = f2bf(acc[i][j][r] + bv);
      }
    }
  }
}

// ---------- GEMM: C[m,n] = sum_k A[m,k]*B[n,k] (+ bias[n])  (bf16 in, fp32 acc) ----------
// 128x128 tile, BK=64 as two stride-32 subtiles sharing one barrier pair.
// Used for the output projection: direct (no split-K), bias folded, f32 out.
template <typename OutT>
__global__ __launch_bounds__(256, 2) void gemm_bt_bias(
    const bf16_t* __restrict__ A,    // [M, K] row-major, bf16
    const bf16_t* __restrict__ B,    // [N, K] row-major, bf16
    const float*  __restrict__ bias, // [N] f32, or nullptr
    OutT* __restrict__ C,            // [M, N]
    int M, int N, int K)
{
  __shared__ bf16_t As[2][128 * 32];   // 8 KB per subtile
  __shared__ bf16_t Bs[2][128 * 32];

  const int tid  = threadIdx.x;
  const int lane = tid & 63;
  const int wave = tid >> 6;
  const int m0 = blockIdx.y * 128;
  const int n0 = blockIdx.x * 128;
  const int mw = (wave >> 1) * 64;
  const int nw = (wave & 1) * 64;
  const int lm = lane & 15;   // col (n) of C; row of A/B frag
  const int lq = lane >> 4;   // quad

  f32x4 acc[4][4];
#pragma unroll
  for (int i = 0; i < 4; ++i)
#pragma unroll
    for (int j = 0; j < 4; ++j)
      acc[i][j] = (f32x4){0.f, 0.f, 0.f, 0.f};

  const int ldr = lane >> 2;        // 0..15 : row within 16-row segment
  const int ldc = (lane & 3) * 8;   // 0,8,16,24 : col offset (elems)

  for (int kt = 0; kt < K; kt += 64) {
    // ---- stage A/B 128x64 tiles as 2 subtiles of 128x32 (16B DMA) ----
#pragma unroll
    for (int sub = 0; sub < 2; ++sub) {
#pragma unroll
      for (int r = 0; r < 2; ++r) {
        const int seg = wave * 2 + r;          // 0..7, wave-uniform
        const int row = seg * 16 + ldr;        // 0..127
        const int col = kt + sub * 32 + ldc;
        const bf16_t* ga = A + (size_t)(m0 + row) * K + col;
        const bf16_t* gb = B + (size_t)(n0 + row) * K + col;
        __builtin_amdgcn_global_load_lds(
            (const __attribute__((address_space(1))) unsigned int*)ga,
            (__attribute__((address_space(3))) unsigned int*)&As[sub][seg * 512], 16, 0, 0);
        __builtin_amdgcn_global_load_lds(
            (const __attribute__((address_space(1))) unsigned int*)gb,
            (__attribute__((address_space(3))) unsigned int*)&Bs[sub][seg * 512], 16, 0, 0);
      }
    }
    __syncthreads();

#pragma unroll
    for (int sub = 0; sub < 2; ++sub) {
      bf16x8 af[4], bfq[4];
#pragma unroll
      for (int i = 0; i < 4; ++i)
        af[i] = *(const bf16x8*)&As[sub][(mw + i * 16 + lm) * 32 + lq * 8];
#pragma unroll
      for (int j = 0; j < 4; ++j)
        bfq[j] = *(const bf16x8*)&Bs[sub][(nw + j * 16 + lm) * 32 + lq * 8];

#pragma unroll
      for (int i = 0; i < 4; ++i)
#pragma unroll
        for (int j = 0; j < 4; ++j)
          acc[i][j] = __builtin_amdgcn_mfma_f32_16x16x32_bf16(af[i], bfq[j], acc[i][j], 0, 0, 0);
    }

    __syncthreads();
  }

  // ---- epilogue: D mapping col=lane&15, row=(lane>>4)*4+reg ----
#pragma unroll
  for (int i = 0; i < 4; ++i) {
#pragma unroll
    for (int j = 0; j < 4; ++j) {
      const int n = n0 + nw + j * 16 + lm;
      const float bv = bias ? bias[n] : 0.f;
#pragma unroll
      for (int r = 0; r < 4; ++r) {
        const int m = m0 + mw + i * 16 + lq * 4 + r;
        store_out(&C[(size_t)m * N + n], acc[i][j][r] + bv);
      }
    }
  }
}

// ---------- fused: partial RoPE (rd=32, in place on q/k) + V transpose ----------
// vtrans role: blocks [0, 1024)      -- reads v slice of qkv -> vtg
// rope role:   blocks [1024, 3072)   -- grid-stride x4 over 8192 chunks (q,k slices)
constexpr int TSTR = 82;   // vtrans LDS tile row stride (even -> aligned u32 writes)
__global__ void rope_vtrans(bf16_t* __restrict__ qkv,
                            const float* __restrict__ cosb,
                            const float* __restrict__ sinb,
                            bf16_t* __restrict__ vtg)
{
  __shared__ bf16_t T[64 * TSTR];
  const int tid = threadIdx.x;

  if (blockIdx.x >= 1024) {
    // ---- RoPE: tmp = concat(x[16:32], x[0:16]) (NO negation); out = x*cos + tmp*sin ----
    for (int j = blockIdx.x - 1024; j < 8192; j += 2048) {
      const int t = j * 256 + tid;  // SEQ*NH*2*16 total
      const int i  = t & 15;
      const int qk = (t >> 4) & 1;
      const int h  = (t >> 5) & 31;
      const int s  = t >> 10;
      const size_t base = (size_t)s * OP + qk * NE + h * HD;
      const float xi = bf2f(qkv[base + i]);
      const float xj = bf2f(qkv[base + i + 16]);
      const float c1 = cosb[s * 32 + i];
      const float s1 = sinb[s * 32 + i];
      const float c2 = cosb[s * 32 + i + 16];
      const float s2 = sinb[s * 32 + i + 16];
      qkv[base + i]      = f2bf(xi * c1 + xj * s1);
      qkv[base + i + 16] = f2bf(xj * c2 + xi * s2);
    }
    return;
  }

  // ---- vtrans: vtg[h][d][s] = qkv[s][2*NE + h*HD + d] ----
  const int vb = blockIdx.x;             // 0..1023
  const int h  = vb >> 5;
  const int sb = (vb & 31) * 64;
  const int voff = 2 * NE + h * HD;

  // stage [64 rows][80 dims] = 2560 u32
#pragma unroll
  for (int i = 0; i < 10; ++i) {
    const int u = i * 256 + tid;
    const int row = u / 40, c = u % 40;
    const unsigned int w = *(const unsigned int*)(qkv + (size_t)(sb + row) * OP + voff + 2 * c);
    *(unsigned int*)&T[row * TSTR + 2 * c] = w;
  }
  __syncthreads();

  // write out transposed: thread (d, sp) packs seq pair -> u32
  bf16_t* vh = vtg + (size_t)h * HD * SEQ;
#pragma unroll
  for (int i = 0; i < 10; ++i) {
    const int u = i * 256 + tid;
    const int d = u >> 5, sp = u & 31;
    const unsigned int lo = T[(2 * sp) * TSTR + d];
    const unsigned int hi = T[(2 * sp + 1) * TSTR + d];
    *(unsigned int*)(vh + (size_t)d * SEQ + sb + 2 * sp) = lo | (hi << 16);
  }
}

// ---------- MFMA flash attention (QBLK=128, 32 q per wave) ----------
// 256 equal-work blocks: block (h = id&31, u = id>>5 in 0..7) processes q-tiles
// {u, 15-u} of 128 rows each -> exactly 34 key-tiles per block.
// __launch_bounds__(256, 2): VGPR <= 256 so TWO blocks co-reside per CU
// (LDS 2 x 69.6 KB = 139 KB <= 160 KB) -> 8 waves/CU.
// 4 waves; wave w owns q rows [q0+32w, q0+32w+32) as TWO 16-row B-fragments
// sharing kf/vf LDS reads. K/V double-buffered, one barrier per key-tile.
constexpr int KSTR = 104;  // Ks row stride (elems): 80 data + 24 junk (conflict-free b128)
constexpr int VSTR = 72;   // Vt row stride: 64 keys + 8 junk (9 x 16B chunks/row)
constexpr int PSTR = 72;   // Ps row stride

__global__ __launch_bounds__(256, 2) void attn_mfma(
    const bf16_t* __restrict__ qkv, const bf16_t* __restrict__ vtg,
    bf16_t* __restrict__ aout)
{
  __shared__ bf16_t Ks[2][13 * 512];     // 2 x 13312 B  [key][104] flat (13 segs of 512)
  __shared__ bf16_t Vt[2][12 * 512];     // 2 x 12288 B  [dim][72] flat (rows 80..85 junk)
  __shared__ bf16_t Ps[4][32 * PSTR];    //     18432 B  per-wave [q 0..31][72]
                                         // total 69632 B -> 2 blocks/CU

  const int id = blockIdx.x;             // 0..255
  const int h  = id & 31;
  const int uu = id >> 5;                // 0..7
  const int tid  = threadIdx.x;
  const int lane = tid & 63;
  const int wave = tid >> 6;
  const int lm   = lane & 15;
  const int quad = lane >> 4;

  const int koff = NE + h * HD;
  const bf16_t* vh = vtg + (size_t)h * HD * SEQ;
  const float EC = 0.1118033988749895f * 1.4426950408889634f;  // 1/sqrt(80) * log2(e)

  // ---- K-stage constants: [64][104] = 13 segs of 512; wave w: segs 3w..3w+2, wave3 also 12 ----
  int kofs[4];
#pragma unroll
  for (int r = 0; r < 4; ++r) {
    const int seg = (r < 3) ? wave * 3 + r : 12;
    const int e = seg * 512 + lane * 8;             // element idx in [64][104]
    const int row = e / KSTR, c = e % KSTR;
    kofs[r] = row * OP + (c < 80 ? c : c - 24);     // junk cols read finite data (x0 later)
  }
  // ---- V-stage constants: flat [d][72], 72 = 9 aligned 16B chunks per row ----
  int vofs[3];
#pragma unroll
  for (int r = 0; r < 3; ++r) {
    const int e = (wave * 3 + r) * 512 + lane * 8;  // element idx in [85][72]
    int row = e / 72;
    const int c = e % 72;
    if (row >= 80) row -= 80;                        // tail segs read junk (never read back)
    vofs[r] = row * SEQ + (c < 64 ? c : c - 16);     // junk chunk re-reads cols 48..63
  }

  // ---- stage one K/V tile (key base kb) into buffer bsel ----
  auto stage_tile = [&](int kb, int bsel) {
#pragma unroll
    for (int r = 0; r < 3; ++r) {
      const bf16_t* gk = qkv + (size_t)kb * OP + koff + kofs[r];
      __builtin_amdgcn_global_load_lds(
          (const __attribute__((address_space(1))) unsigned int*)gk,
          (__attribute__((address_space(3))) unsigned int*)&Ks[bsel][(wave * 3 + r) * 512],
          16, 0, 0);
      const bf16_t* gv = vh + kb + vofs[r];
      __builtin_amdgcn_global_load_lds(
          (const __attribute__((address_space(1))) unsigned int*)gv,
          (__attribute__((address_space(3))) unsigned int*)&Vt[bsel][(wave * 3 + r) * 512],
          16, 0, 0);
    }
    if (wave == 3) {   // 13th K segment
      const bf16_t* gk = qkv + (size_t)kb * OP + koff + kofs[3];
      __builtin_amdgcn_global_load_lds(
          (const __attribute__((address_space(1))) unsigned int*)gk,
          (__attribute__((address_space(3))) unsigned int*)&Ks[bsel][12 * 512],
          16, 0, 0);
    }
  };

#pragma unroll 1
  for (int pass = 0; pass < 2; ++pass) {
    const int jt = pass ? 15 - uu : uu;    // q-tile index (128-row tiles)
    const int q0 = jt * 128;
    const int qw = q0 + 32 * wave;         // wave's q base (32 rows)

    // ---- Q fragments (B operand), two q-halves: rows qw+qh*16+lm, cols quad*8+j ----
    bf16x8 qf[2][3];
#pragma unroll
    for (int qh = 0; qh < 2; ++qh) {
      const bf16_t* q_r = qkv + (size_t)(qw + qh * 16 + lm) * OP + h * HD;
#pragma unroll
      for (int ks = 0; ks < 3; ++ks) {
        const int col = ks * 32 + quad * 8;
        if (col < 80) qf[qh][ks] = *(const bf16x8*)(q_r + col);
        else          qf[qh][ks] = (bf16x8){0,0,0,0,0,0,0,0};  // 80..95 pad
      }
    }

    f32x4 oacc[5][2];
#pragma unroll
    for (int mt = 0; mt < 5; ++mt)
#pragma unroll
      for (int qh = 0; qh < 2; ++qh) oacc[mt][qh] = (f32x4){0.f,0.f,0.f,0.f};
    float lsum[2] = {0.f, 0.f};

    const int ntiles = 2 * jt + 2;   // 64-key tiles covering [0, q0+128)
    // prologue: stage tile 0 into buffer 0
    stage_tile(0, 0);
    __syncthreads();

    int buf = 0;
#pragma unroll 1
    for (int t = 0; t < ntiles; ++t) {
      // ---- stage next tile into the other buffer (overlaps compute below) ----
      if (t + 1 < ntiles) stage_tile((t + 1) * 64, buf ^ 1);

      const bf16_t* Kb = &Ks[buf][0];
      const bf16_t* Vb = &Vt[buf][0];

      // ---- S^T = K·Q^T : D[m=key][n=q], both q-halves share kf reads ----
      f32x4 sacc[4][2];
#pragma unroll
      for (int mt = 0; mt < 4; ++mt)
#pragma unroll
        for (int qh = 0; qh < 2; ++qh) sacc[mt][qh] = (f32x4){0.f,0.f,0.f,0.f};
#pragma unroll
      for (int ks = 0; ks < 3; ++ks) {
        bf16x8 kf[4];
#pragma unroll
        for (int mt = 0; mt < 4; ++mt)
          kf[mt] = *(const bf16x8*)&Kb[(mt * 16 + lm) * KSTR + ks * 32 + quad * 8];
        __builtin_amdgcn_s_setprio(1);
#pragma unroll
        for (int mt = 0; mt < 4; ++mt)
#pragma unroll
          for (int qh = 0; qh < 2; ++qh)
            sacc[mt][qh] = __builtin_amdgcn_mfma_f32_16x16x32_bf16(kf[mt], qf[qh][ks], sacc[mt][qh], 0, 0, 0);
        __builtin_amdgcn_s_setprio(0);
      }

      // ---- softmax (exp2, no max) + pack P; causal mask on the last TWO tiles ----
      const int kb = t * 64;
      const int keyb = kb + quad * 4;
      if (t + 2 >= ntiles) {
#pragma unroll
        for (int qh = 0; qh < 2; ++qh) {
          const int qg = qw + qh * 16 + lm;
#pragma unroll
          for (int mt = 0; mt < 4; ++mt) {
            float ps[4];
#pragma unroll
            for (int r = 0; r < 4; ++r) {
              float p = exp2_hw(sacc[mt][qh][r] * EC);
              p = (keyb + mt * 16 + r > qg) ? 0.f : p;   // causal
              ps[r] = p;
            }
            lsum[qh] += (ps[0] + ps[1]) + (ps[2] + ps[3]);
            ushort4 pk;
            pk.x = f2bf(ps[0]); pk.y = f2bf(ps[1]); pk.z = f2bf(ps[2]); pk.w = f2bf(ps[3]);
            *(ushort4*)&Ps[wave][(qh * 16 + lm) * PSTR + mt * 16 + quad * 4] = pk;
          }
        }
      } else {
#pragma unroll
        for (int qh = 0; qh < 2; ++qh) {
#pragma unroll
          for (int mt = 0; mt < 4; ++mt) {
            float ps[4];
#pragma unroll
            for (int r = 0; r < 4; ++r) ps[r] = exp2_hw(sacc[mt][qh][r] * EC);
            lsum[qh] += (ps[0] + ps[1]) + (ps[2] + ps[3]);
            ushort4 pk;
            pk.x = f2bf(ps[0]); pk.y = f2bf(ps[1]); pk.z = f2bf(ps[2]); pk.w = f2bf(ps[3]);
            *(ushort4*)&Ps[wave][(qh * 16 + lm) * PSTR + mt * 16 + quad * 4] = pk;
          }
        }
      }

      // ---- PV : O^T[d][q] += Vt·P; vf reads shared across both q-halves ----
#pragma unroll
      for (int ks = 0; ks < 2; ++ks) {
        bf16x8 vf[5], pf[2];
#pragma unroll
        for (int mt = 0; mt < 5; ++mt)
          vf[mt] = *(const bf16x8*)&Vb[(mt * 16 + lm) * VSTR + ks * 32 + quad * 8];
#pragma unroll
        for (int qh = 0; qh < 2; ++qh)
          pf[qh] = *(const bf16x8*)&Ps[wave][(qh * 16 + lm) * PSTR + ks * 32 + quad * 8];
        __builtin_amdgcn_s_setprio(1);
#pragma unroll
        for (int mt = 0; mt < 5; ++mt)
#pragma unroll
          for (int qh = 0; qh < 2; ++qh)
            oacc[mt][qh] = __builtin_amdgcn_mfma_f32_16x16x32_bf16(vf[mt], pf[qh], oacc[mt][qh], 0, 0, 0);
        __builtin_amdgcn_s_setprio(0);
      }

      // one barrier per tile: all reads of buf done; next-tile staging (into buf^1)
      // was issued a full compute-phase ago, so the implicit vmcnt(0) is cheap.
      __syncthreads();
      buf ^= 1;
    }

    // ---- epilogue: reduce l across quads, normalize, write aout (two q-rows) ----
#pragma unroll
    for (int qh = 0; qh < 2; ++qh) {
      float l = lsum[qh];
      l += __shfl_xor(l, 16);
      l += __shfl_xor(l, 32);
      const float inv = 1.f / l;
      bf16_t* base = aout + (size_t)(qw + qh * 16 + lm) * NE + h * HD + quad * 4;
#pragma unroll
      for (int mt = 0; mt < 5; ++mt) {   // d = mt*16 + quad*4 + r
        ushort4 st;
        st.x = f2bf(oacc[mt][qh][0] * inv);
        st.y = f2bf(oacc[mt][qh][1] * inv);
        st.z = f2bf(oacc[mt][qh][2] * inv);
        st.w = f2bf(oacc[mt][qh][3] * inv);
        *(ushort4*)(base + mt * 16) = st;
      }
    }
  }
}

// ---------- launch ----------
extern "C" void kernel_launch(void* const* d_in, const int* in_sizes, int n_in,
                              void* d_out, int out_size, void* d_ws, size_t ws_size,
                              hipStream_t stream)
{
  const float* hs   = (const float*)d_in[0];  // [1, 2048, 2560] f32
  const float* wqkv = (const float*)d_in[1];  // [7680, 2560] f32
  const float* bqkv = (const float*)d_in[2];  // [7680] f32
  const float* wout = (const float*)d_in[3];  // [2560, 2560] f32
  const float* bout = (const float*)d_in[4];  // [2560] f32
  const float* cosb = (const float*)d_in[5];  // [2048, 32] f32
  const float* sinb = (const float*)d_in[6];  // [2048, 32] f32

  // workspace layout (bf16): ~105 MB total
  bf16_t* hs_bf   = (bf16_t*)d_ws;                        // 2048*2560  (dead after QKV)
  bf16_t* wqkv_bf = hs_bf   + (size_t)SEQ * NE;           // 7680*2560  (dead after QKV)
  bf16_t* wout_bf = wqkv_bf + (size_t)OP * NE;            // 2560*2560  (live until proj)
  bf16_t* qkv     = wout_bf + (size_t)NE * NE;            // 2048*7680
  bf16_t* aout    = qkv     + (size_t)SEQ * OP;           // 2048*2560
  float*  out     = (float*)d_out;                        // [2048, 2560] f32
  // overlay (stream-ordered, no overlap in live ranges):
  bf16_t* vtg     = hs_bf;          // [NH][HD][SEQ] 10.5 MB, live vtrans->attn

  // 0) f32 -> bf16 conversions (grid-stride, 2048 blocks)
  cvt3<<<2048, 256, 0, stream>>>(hs, wqkv, wout, hs_bf, wqkv_bf, wout_bf);

  // 1) QKV projection: qkv = hs @ Wqkv^T + b   (256x256 single-barrier pipelined, 240 blocks)
  gemm256_bt_bias<<<dim3(OP / 256, SEQ / 256), 512, 0, stream>>>(
      hs_bf, wqkv_bf, bqkv, qkv, SEQ, OP, NE);
  // 2) fused partial RoPE (in place on q,k) + V transpose -> vtg[h][d][s]  (3072 blocks)
  rope_vtrans<<<1024 + 2048, 256, 0, stream>>>(qkv, cosb, sinb, vtg);
  // 3) MFMA flash attention -> aout [2048, 2560]  (256 equal-work blocks, 2 blocks/CU)
  attn_mfma<<<256, 256, 0, stream>>>(qkv, vtg, aout);
  // 4) output projection, direct (320 blocks, bias folded, f32 out): no split-K,
  //    no partial buffers, no reduce pass (-1 dispatch, -94 MB HBM traffic)
  gemm_bt_bias<float><<<dim3(NE / 128, SEQ / 128), 256, 0, stream>>>(
      aout, wout_bf, bout, out, SEQ, NE, NE);
}

// Round 11
// 353.104 us; speedup vs baseline: 1.0520x; 1.0520x over previous
//
#include <hip/hip_runtime.h>
#include <cstdint>
#include <cstddef>

// ---------- types / helpers ----------
typedef unsigned short bf16_t;
typedef __attribute__((ext_vector_type(8))) short bf16x8;   // 8 bf16 in 4 VGPRs (MFMA A/B frag)
typedef __attribute__((ext_vector_type(4))) float f32x4;    // MFMA C/D frag

__device__ __forceinline__ float bf2f(bf16_t b) {
  unsigned int u = ((unsigned int)b) << 16;
  return __builtin_bit_cast(float, u);
}
__device__ __forceinline__ bf16_t f2bf(float f) {
  unsigned int u = __builtin_bit_cast(unsigned int, f);
  u += 0x7fffu + ((u >> 16) & 1u);   // round-to-nearest-even
  return (bf16_t)(u >> 16);
}
__device__ __forceinline__ float exp2_hw(float x) {
  return __builtin_amdgcn_exp2f(x);   // v_exp_f32: D = 2^S0
}

// Problem constants
constexpr int SEQ = 2048, NE = 2560, NH = 32, HD = 80, OP = 7680;

// ---------- fused f32 -> bf16 convert for hs / wqkv / wout (one launch) ----------
__global__ void cvt3(const float* __restrict__ s0, const float* __restrict__ s1,
                     const float* __restrict__ s2, bf16_t* __restrict__ d0,
                     bf16_t* __restrict__ d1, bf16_t* __restrict__ d2)
{
  constexpr int N0 = SEQ * NE / 4, N1 = OP * NE / 4;
  int t = blockIdx.x * 256 + threadIdx.x;
  const float* s; bf16_t* d;
  if (t < N0)            { s = s0; d = d0; }
  else if (t < N0 + N1)  { s = s1; d = d1; t -= N0; }
  else                   { s = s2; d = d2; t -= N0 + N1; }
  float4 v = ((const float4*)s)[t];
  ushort4 o;
  o.x = f2bf(v.x); o.y = f2bf(v.y); o.z = f2bf(v.z); o.w = f2bf(v.w);
  ((ushort4*)d)[t] = o;
}

// ---------- store helpers (GEMM output: bf16 or f32) ----------
__device__ __forceinline__ void store_out(bf16_t* p, float v) { *p = f2bf(v); }
__device__ __forceinline__ void store_out(float* p, float v)  { *p = v; }

// ============================================================================
// 256x256 GEMM (QKV): C[m,n] = sum_k A[m,k]*B[n,k] + bias[n]
// 8 waves (2M x 4N), BK=64, 2 K-tile LDS double buffer (128 KiB), T2 swizzle.
// ONE barrier per K-tile; operand ds_reads issued one phase ahead of use.
// (Best-measured QKV structure: ~87 us on fast containers, MfmaUtil ~38%.)
// ============================================================================
__global__ __launch_bounds__(512, 2) void gemm256_bt_bias(
    const bf16_t* __restrict__ A,    // [M, K] row-major bf16
    const bf16_t* __restrict__ B,    // [N, K] row-major bf16
    const float*  __restrict__ bias, // [N] f32
    bf16_t* __restrict__ C,          // [M, N] bf16
    int M, int N, int K)
{
  __shared__ bf16_t As[2][256 * 64];   // 32 KB per buffer
  __shared__ bf16_t Bs[2][256 * 64];

  const int tid  = threadIdx.x;
  const int lane = tid & 63;
  const int wave = tid >> 6;
  const int wm   = wave >> 2;    // 0..1  (M half)
  const int wn   = wave & 3;     // 0..3  (N quarter)
  const int lm   = lane & 15;
  const int quad = lane >> 4;
  const int m0 = blockIdx.y * 256;
  const int n0 = blockIdx.x * 256;
  const int NT = K / 64;

  // ---- staging per-lane constants (inverse-swizzled global source) ----
  const int srow = lane >> 3;                      // 0..7
  const int scol = ((lane & 7) ^ srow) * 8;        // logical elem col for this lane's slot

  auto stage = [&](const bf16_t* __restrict__ P, int R0, int K0, int H, bf16_t* DST) {
#pragma unroll
    for (int cc = 0; cc < 2; ++cc) {
      const int seg = wave * 2 + cc;               // 0..15 (wave-uniform)
      const bf16_t* src = P + (size_t)(R0 + H * 128 + seg * 8 + srow) * K + K0 + scol;
      __builtin_amdgcn_global_load_lds(
          (const __attribute__((address_space(1))) unsigned int*)src,
          (__attribute__((address_space(3))) unsigned int*)(DST + H * 8192 + seg * 512),
          16, 0, 0);
    }
  };

  // ---- swizzled ds_read slot offsets (lane-constant) ----
  const int xk0 = ((0 + quad) ^ (lm & 7)) * 8;     // kk=0: logical slot quad
  const int xk1 = ((4 + quad) ^ (lm & 7)) * 8;     // kk=1: logical slot 4+quad

  const int AOFF = (wm * 128 + lm) * 64;           // + h*4096 + i*1024 + xk
  const int BOFF = (wn * 64  + lm) * 64;           // + j*1024 (+2048 for b23) + xk

  f32x4 acc[8][4];
#pragma unroll
  for (int i = 0; i < 8; ++i)
#pragma unroll
    for (int j = 0; j < 4; ++j)
      acc[i][j] = (f32x4){0.f, 0.f, 0.f, 0.f};

  // ---- prologue: stage tile0 (oldest 8) then tile1 (next 8) ----
  stage(A, m0, 0, 0, As[0]);  stage(A, m0, 0, 1, As[0]);
  stage(B, n0, 0, 0, Bs[0]);  stage(B, n0, 0, 1, Bs[0]);
  stage(A, m0, 64, 0, As[1]); stage(A, m0, 64, 1, As[1]);
  stage(B, n0, 64, 0, Bs[1]); stage(B, n0, 64, 1, Bs[1]);

  asm volatile("s_waitcnt vmcnt(8)" ::: "memory");   // tile0 staged
  __builtin_amdgcn_s_barrier();
  __builtin_amdgcn_sched_barrier(0);

  bf16x8 a[4][2], b01[2][2], b23[2][2];
  // pre-read: b01 = B(0)[n 0:32], a = A(0)[m 0:64]
#pragma unroll
  for (int j = 0; j < 2; ++j) {
    b01[j][0] = *(const bf16x8*)(&Bs[0][BOFF + j * 1024 + xk0]);
    b01[j][1] = *(const bf16x8*)(&Bs[0][BOFF + j * 1024 + xk1]);
  }
#pragma unroll
  for (int i = 0; i < 4; ++i) {
    a[i][0] = *(const bf16x8*)(&As[0][AOFF + i * 1024 + xk0]);
    a[i][1] = *(const bf16x8*)(&As[0][AOFF + i * 1024 + xk1]);
  }
  __builtin_amdgcn_sched_barrier(0);

  for (int t = 0; t < NT; ++t) {
    const int c = t & 1;
    const bf16_t* Ac = &As[c][0];
    const bf16_t* Bc = &Bs[c][0];
    const bf16_t* An = &As[c ^ 1][0];
    const bf16_t* Bn = &Bs[c ^ 1][0];

    // ===== ph0: acc[0..3][0..1] += a(A half0) x b01 =====
    __builtin_amdgcn_s_setprio(1);
#pragma unroll
    for (int kk = 0; kk < 2; ++kk)
#pragma unroll
      for (int i = 0; i < 2; ++i)
#pragma unroll
        for (int j = 0; j < 2; ++j)
          acc[i][j] = __builtin_amdgcn_mfma_f32_16x16x32_bf16(a[i][kk], b01[j][kk], acc[i][j], 0, 0, 0);
    __builtin_amdgcn_s_setprio(0);
    // issue b23 reads (dead regs; used in ph1)
#pragma unroll
    for (int j = 0; j < 2; ++j) {
      b23[j][0] = *(const bf16x8*)(Bc + BOFF + (2 + j) * 1024 + xk0);
      b23[j][1] = *(const bf16x8*)(Bc + BOFF + (2 + j) * 1024 + xk1);
    }
    __builtin_amdgcn_sched_barrier(0);
    __builtin_amdgcn_s_setprio(1);
#pragma unroll
    for (int kk = 0; kk < 2; ++kk)
#pragma unroll
      for (int i = 2; i < 4; ++i)
#pragma unroll
        for (int j = 0; j < 2; ++j)
          acc[i][j] = __builtin_amdgcn_mfma_f32_16x16x32_bf16(a[i][kk], b01[j][kk], acc[i][j], 0, 0, 0);
    __builtin_amdgcn_s_setprio(0);
    __builtin_amdgcn_sched_barrier(0);

    // ===== ph1: acc[0..3][2..3] += a(A half0) x b23 =====
    __builtin_amdgcn_s_setprio(1);
#pragma unroll
    for (int kk = 0; kk < 2; ++kk)
#pragma unroll
      for (int i = 0; i < 4; ++i)
#pragma unroll
        for (int j = 0; j < 2; ++j)
          acc[i][2 + j] = __builtin_amdgcn_mfma_f32_16x16x32_bf16(a[i][kk], b23[j][kk], acc[i][2 + j], 0, 0, 0);
    __builtin_amdgcn_s_setprio(0);
    // issue a = A half1 reads (a dead after ph1; used in ph2)
#pragma unroll
    for (int i = 0; i < 4; ++i) {
      a[i][0] = *(const bf16x8*)(Ac + AOFF + 4096 + i * 1024 + xk0);
      a[i][1] = *(const bf16x8*)(Ac + AOFF + 4096 + i * 1024 + xk1);
    }
    __builtin_amdgcn_sched_barrier(0);

    // ===== ph2: acc[4..7][0..1] += a(A half1) x b01 =====
    __builtin_amdgcn_s_setprio(1);
#pragma unroll
    for (int kk = 0; kk < 2; ++kk)
#pragma unroll
      for (int i = 0; i < 4; ++i)
#pragma unroll
        for (int j = 0; j < 2; ++j)
          acc[4 + i][j] = __builtin_amdgcn_mfma_f32_16x16x32_bf16(a[i][kk], b01[j][kk], acc[4 + i][j], 0, 0, 0);
    __builtin_amdgcn_s_setprio(0);
    __builtin_amdgcn_sched_barrier(0);

    // ---- the ONE sync point per K-tile ----
    asm volatile("s_waitcnt lgkmcnt(0)" ::: "memory");   // ~free: all reads consumed
    asm volatile("s_waitcnt vmcnt(0)"  ::: "memory");    // t+1 staging (issued 4 phases ago)
    __builtin_amdgcn_s_barrier();
    __builtin_amdgcn_sched_barrier(0);
    // issue b01 = B(t+1)[n 0:32] from next buffer (b01 dead)
    if (t + 1 < NT) {
#pragma unroll
      for (int j = 0; j < 2; ++j) {
        b01[j][0] = *(const bf16x8*)(Bn + BOFF + j * 1024 + xk0);
        b01[j][1] = *(const bf16x8*)(Bn + BOFF + j * 1024 + xk1);
      }
    }
    __builtin_amdgcn_sched_barrier(0);

    // ===== ph3: acc[4..7][2..3] += a(A half1) x b23 =====
    __builtin_amdgcn_s_setprio(1);
#pragma unroll
    for (int kk = 0; kk < 2; ++kk)
#pragma unroll
      for (int i = 0; i < 4; ++i)
#pragma unroll
        for (int j = 0; j < 2; ++j)
          acc[4 + i][2 + j] = __builtin_amdgcn_mfma_f32_16x16x32_bf16(a[i][kk], b23[j][kk], acc[4 + i][2 + j], 0, 0, 0);
    __builtin_amdgcn_s_setprio(0);
    // stage tile t+2 into buffer c (all buffer-c reads drained before the barrier)
    if (t + 2 < NT) {
      stage(B, n0, (t + 2) * 64, 0, (bf16_t*)Bs[c]);
      stage(B, n0, (t + 2) * 64, 1, (bf16_t*)Bs[c]);
      stage(A, m0, (t + 2) * 64, 0, (bf16_t*)As[c]);
      stage(A, m0, (t + 2) * 64, 1, (bf16_t*)As[c]);
    }
    // issue a = A(t+1)[m 0:64] from next buffer (a dead after ph3)
    if (t + 1 < NT) {
#pragma unroll
      for (int i = 0; i < 4; ++i) {
        a[i][0] = *(const bf16x8*)(An + AOFF + i * 1024 + xk0);
        a[i][1] = *(const bf16x8*)(An + AOFF + i * 1024 + xk1);
      }
    }
    __builtin_amdgcn_sched_barrier(0);
  }

  // ---- epilogue: D mapping col=lane&15, row=quad*4+reg ----
#pragma unroll
  for (int i = 0; i < 8; ++i) {
#pragma unroll
    for (int j = 0; j < 4; ++j) {
      const int n = n0 + wn * 64 + j * 16 + lm;
      const float bv = bias ? bias[n] : 0.f;
#pragma unroll
      for (int r = 0; r < 4; ++r) {
        const int m = m0 + wm * 128 + i * 16 + quad * 4 + r;
        C[(size_t)m * N + n] = f2bf(acc[i][j][r] + bv);
      }
    }
  }
}

// ---------- GEMM: C[m,n] = sum_k A[m,k]*B[n,k] (+ bias[n])  (bf16 in, fp32 acc) ----------
// 128x128 tile, BK=64 as two stride-32 subtiles sharing one barrier pair.
// Optional split-K via blockIdx.z (partials, no bias). Used for the output projection.
template <typename OutT>
__global__ __launch_bounds__(256, 2) void gemm_bt_bias(
    const bf16_t* __restrict__ A,    // [M, K] row-major, bf16
    const bf16_t* __restrict__ B,    // [N, K] row-major, bf16
    const float*  __restrict__ bias, // [N] f32, or nullptr
    OutT* __restrict__ C,            // [gridDim.z][M, N]
    int M, int N, int K, int klen)   // klen = K / gridDim.z
{
  __shared__ bf16_t As[2][128 * 32];   // 8 KB per subtile
  __shared__ bf16_t Bs[2][128 * 32];

  const int tid  = threadIdx.x;
  const int lane = tid & 63;
  const int wave = tid >> 6;
  const int m0 = blockIdx.y * 128;
  const int n0 = blockIdx.x * 128;
  const int kbeg = blockIdx.z * klen;
  OutT* Cz = C + (size_t)blockIdx.z * M * N;
  const int mw = (wave >> 1) * 64;
  const int nw = (wave & 1) * 64;
  const int lm = lane & 15;   // col (n) of C; row of A/B frag
  const int lq = lane >> 4;   // quad

  f32x4 acc[4][4];
#pragma unroll
  for (int i = 0; i < 4; ++i)
#pragma unroll
    for (int j = 0; j < 4; ++j)
      acc[i][j] = (f32x4){0.f, 0.f, 0.f, 0.f};

  const int ldr = lane >> 2;        // 0..15 : row within 16-row segment
  const int ldc = (lane & 3) * 8;   // 0,8,16,24 : col offset (elems)

  for (int kt = kbeg; kt < kbeg + klen; kt += 64) {
    // ---- stage A/B 128x64 tiles as 2 subtiles of 128x32 (16B DMA) ----
#pragma unroll
    for (int sub = 0; sub < 2; ++sub) {
#pragma unroll
      for (int r = 0; r < 2; ++r) {
        const int seg = wave * 2 + r;          // 0..7, wave-uniform
        const int row = seg * 16 + ldr;        // 0..127
        const int col = kt + sub * 32 + ldc;
        const bf16_t* ga = A + (size_t)(m0 + row) * K + col;
        const bf16_t* gb = B + (size_t)(n0 + row) * K + col;
        __builtin_amdgcn_global_load_lds(
            (const __attribute__((address_space(1))) unsigned int*)ga,
            (__attribute__((address_space(3))) unsigned int*)&As[sub][seg * 512], 16, 0, 0);
        __builtin_amdgcn_global_load_lds(
            (const __attribute__((address_space(1))) unsigned int*)gb,
            (__attribute__((address_space(3))) unsigned int*)&Bs[sub][seg * 512], 16, 0, 0);
      }
    }
    __syncthreads();

#pragma unroll
    for (int sub = 0; sub < 2; ++sub) {
      bf16x8 af[4], bfq[4];
#pragma unroll
      for (int i = 0; i < 4; ++i)
        af[i] = *(const bf16x8*)&As[sub][(mw + i * 16 + lm) * 32 + lq * 8];
#pragma unroll
      for (int j = 0; j < 4; ++j)
        bfq[j] = *(const bf16x8*)&Bs[sub][(nw + j * 16 + lm) * 32 + lq * 8];

#pragma unroll
      for (int i = 0; i < 4; ++i)
#pragma unroll
        for (int j = 0; j < 4; ++j)
          acc[i][j] = __builtin_amdgcn_mfma_f32_16x16x32_bf16(af[i], bfq[j], acc[i][j], 0, 0, 0);
    }

    __syncthreads();
  }

  // ---- epilogue: D mapping col=lane&15, row=(lane>>4)*4+reg ----
#pragma unroll
  for (int i = 0; i < 4; ++i) {
#pragma unroll
    for (int j = 0; j < 4; ++j) {
      const int n = n0 + nw + j * 16 + lm;
      const float bv = bias ? bias[n] : 0.f;
#pragma unroll
      for (int r = 0; r < 4; ++r) {
        const int m = m0 + mw + i * 16 + lq * 4 + r;
        store_out(&Cz[(size_t)m * N + n], acc[i][j][r] + bv);
      }
    }
  }
}

// ---------- split-K reduce: out = p[0] + p[1] + bias ----------
__global__ void reduce2_bias(const float* __restrict__ p, const float* __restrict__ bias,
                             float* __restrict__ out)
{
  const int t = blockIdx.x * 256 + threadIdx.x;   // float4 index over [SEQ][NE]
  const float4 a = ((const float4*)p)[t];
  const float4 b = ((const float4*)(p + (size_t)SEQ * NE))[t];
  const float4 bv = ((const float4*)bias)[t % (NE / 4)];
  float4 r;
  r.x = a.x + b.x + bv.x; r.y = a.y + b.y + bv.y;
  r.z = a.z + b.z + bv.z; r.w = a.w + b.w + bv.w;
  ((float4*)out)[t] = r;
}

// ---------- fused: partial RoPE (rd=32, in place on q/k) + V transpose ----------
// rope role: blocks [0, 8192)   -- writes q,k slices of qkv
// vtrans role: blocks [8192, 9216) -- reads v slice of qkv -> vtg (disjoint data)
constexpr int TSTR = 82;   // vtrans LDS tile row stride (even -> aligned u32 writes)
__global__ void rope_vtrans(bf16_t* __restrict__ qkv,
                            const float* __restrict__ cosb,
                            const float* __restrict__ sinb,
                            bf16_t* __restrict__ vtg)
{
  __shared__ bf16_t T[64 * TSTR];
  const int tid = threadIdx.x;

  if (blockIdx.x < 8192) {
    // ---- RoPE: tmp = concat(x[16:32], x[0:16]) (NO negation); out = x*cos + tmp*sin ----
    const int t = blockIdx.x * 256 + tid;  // SEQ*NH*2*16 total
    const int i  = t & 15;
    const int qk = (t >> 4) & 1;
    const int h  = (t >> 5) & 31;
    const int s  = t >> 10;
    const size_t base = (size_t)s * OP + qk * NE + h * HD;
    const float xi = bf2f(qkv[base + i]);
    const float xj = bf2f(qkv[base + i + 16]);
    const float c1 = cosb[s * 32 + i];
    const float s1 = sinb[s * 32 + i];
    const float c2 = cosb[s * 32 + i + 16];
    const float s2 = sinb[s * 32 + i + 16];
    qkv[base + i]      = f2bf(xi * c1 + xj * s1);
    qkv[base + i + 16] = f2bf(xj * c2 + xi * s2);
    return;
  }

  // ---- vtrans: vtg[h][d][s] = qkv[s][2*NE + h*HD + d] ----
  const int vb = blockIdx.x - 8192;      // 0..1023
  const int h  = vb >> 5;
  const int sb = (vb & 31) * 64;
  const int voff = 2 * NE + h * HD;

  // stage [64 rows][80 dims] = 2560 u32
#pragma unroll
  for (int i = 0; i < 10; ++i) {
    const int u = i * 256 + tid;
    const int row = u / 40, c = u % 40;
    const unsigned int w = *(const unsigned int*)(qkv + (size_t)(sb + row) * OP + voff + 2 * c);
    *(unsigned int*)&T[row * TSTR + 2 * c] = w;
  }
  __syncthreads();

  // write out transposed: thread (d, sp) packs seq pair -> u32
  bf16_t* vh = vtg + (size_t)h * HD * SEQ;
#pragma unroll
  for (int i = 0; i < 10; ++i) {
    const int u = i * 256 + tid;
    const int d = u >> 5, sp = u & 31;
    const unsigned int lo = T[(2 * sp) * TSTR + d];
    const unsigned int hi = T[(2 * sp + 1) * TSTR + d];
    *(unsigned int*)(vh + (size_t)d * SEQ + sb + 2 * sp) = lo | (hi << 16);
  }
}

// ---------- MFMA flash attention (QBLK=128, 32 q per wave, 512 blocks) ----------
// 512 single-pass blocks: x<256 -> jt=x>>5, x>=256 -> jt=15-((x-256)>>5); h=x&31.
// Under round-robin placement CU k hosts blocks {k, k+256} with jt pairs (a,15-a):
// per-CU work == 34 key-tiles (constant) AND two co-resident 4-wave blocks with
// DISJOINT barrier domains -> one block's staging drain hides under the other's
// compute (R7's grid was 256 -> only 1 block/CU; this fills the second slot).
// __launch_bounds__(256,2): VGPR <= 256; LDS 69.6 KB -> 2 blocks/CU (139 KB).
// 4 waves; wave w owns q rows [q0+32w, q0+32w+32) as TWO 16-row B-fragments
// sharing kf/vf LDS reads. K/V double-buffered, one barrier per key-tile.
constexpr int KSTR = 104;  // Ks row stride (elems): 80 data + 24 junk (conflict-free b128)
constexpr int VSTR = 72;   // Vt row stride: 64 keys + 8 junk (9 x 16B chunks/row)
constexpr int PSTR = 72;   // Ps row stride

__global__ __launch_bounds__(256, 2) void attn_mfma(
    const bf16_t* __restrict__ qkv, const bf16_t* __restrict__ vtg,
    bf16_t* __restrict__ aout)
{
  __shared__ bf16_t Ks[2][13 * 512];     // 2 x 13312 B  [key][104] flat (13 segs of 512)
  __shared__ bf16_t Vt[2][12 * 512];     // 2 x 12288 B  [dim][72] flat (rows 80..85 junk)
  __shared__ bf16_t Ps[4][32 * PSTR];    //     18432 B  per-wave [q 0..31][72]
                                         // total 69632 B -> 2 blocks/CU

  const int x  = blockIdx.x;             // 0..511
  const int h  = x & 31;
  const int jt = (x < 256) ? (x >> 5) : 15 - ((x - 256) >> 5);   // zigzag pairing
  const int tid  = threadIdx.x;
  const int lane = tid & 63;
  const int wave = tid >> 6;
  const int lm   = lane & 15;
  const int quad = lane >> 4;

  const int koff = NE + h * HD;
  const bf16_t* vh = vtg + (size_t)h * HD * SEQ;
  const float EC = 0.1118033988749895f * 1.4426950408889634f;  // 1/sqrt(80) * log2(e)

  // ---- K-stage constants: [64][104] = 13 segs of 512; wave w: segs 3w..3w+2, wave3 also 12 ----
  int kofs[4];
#pragma unroll
  for (int r = 0; r < 4; ++r) {
    const int seg = (r < 3) ? wave * 3 + r : 12;
    const int e = seg * 512 + lane * 8;             // element idx in [64][104]
    const int row = e / KSTR, c = e % KSTR;
    kofs[r] = row * OP + (c < 80 ? c : c - 24);     // junk cols read finite data (x0 later)
  }
  // ---- V-stage constants: flat [d][72], 72 = 9 aligned 16B chunks per row ----
  int vofs[3];
#pragma unroll
  for (int r = 0; r < 3; ++r) {
    const int e = (wave * 3 + r) * 512 + lane * 8;  // element idx in [85][72]
    int row = e / 72;
    const int c = e % 72;
    if (row >= 80) row -= 80;                        // tail segs read junk (never read back)
    vofs[r] = row * SEQ + (c < 64 ? c : c - 16);     // junk chunk re-reads cols 48..63
  }

  // ---- stage one K/V tile (key base kb) into buffer bsel ----
  auto stage_tile = [&](int kb, int bsel) {
#pragma unroll
    for (int r = 0; r < 3; ++r) {
      const bf16_t* gk = qkv + (size_t)kb * OP + koff + kofs[r];
      __builtin_amdgcn_global_load_lds(
          (const __attribute__((address_space(1))) unsigned int*)gk,
          (__attribute__((address_space(3))) unsigned int*)&Ks[bsel][(wave * 3 + r) * 512],
          16, 0, 0);
      const bf16_t* gv = vh + kb + vofs[r];
      __builtin_amdgcn_global_load_lds(
          (const __attribute__((address_space(1))) unsigned int*)gv,
          (__attribute__((address_space(3))) unsigned int*)&Vt[bsel][(wave * 3 + r) * 512],
          16, 0, 0);
    }
    if (wave == 3) {   // 13th K segment
      const bf16_t* gk = qkv + (size_t)kb * OP + koff + kofs[3];
      __builtin_amdgcn_global_load_lds(
          (const __attribute__((address_space(1))) unsigned int*)gk,
          (__attribute__((address_space(3))) unsigned int*)&Ks[bsel][12 * 512],
          16, 0, 0);
    }
  };

  const int q0 = jt * 128;
  const int qw = q0 + 32 * wave;         // wave's q base (32 rows)

  // ---- Q fragments (B operand), two q-halves: rows qw+qh*16+lm, cols quad*8+j ----
  bf16x8 qf[2][3];
#pragma unroll
  for (int qh = 0; qh < 2; ++qh) {
    const bf16_t* q_r = qkv + (size_t)(qw + qh * 16 + lm) * OP + h * HD;
#pragma unroll
    for (int ks = 0; ks < 3; ++ks) {
      const int col = ks * 32 + quad * 8;
      if (col < 80) qf[qh][ks] = *(const bf16x8*)(q_r + col);
      else          qf[qh][ks] = (bf16x8){0,0,0,0,0,0,0,0};  // 80..95 pad
    }
  }

  f32x4 oacc[5][2];
#pragma unroll
  for (int mt = 0; mt < 5; ++mt)
#pragma unroll
    for (int qh = 0; qh < 2; ++qh) oacc[mt][qh] = (f32x4){0.f,0.f,0.f,0.f};
  float lsum[2] = {0.f, 0.f};

  const int ntiles = 2 * jt + 2;   // 64-key tiles covering [0, q0+128)
  // prologue: stage tile 0 into buffer 0
  stage_tile(0, 0);
  __syncthreads();

  int buf = 0;
#pragma unroll 1
  for (int t = 0; t < ntiles; ++t) {
    // ---- stage next tile into the other buffer (overlaps compute below) ----
    if (t + 1 < ntiles) stage_tile((t + 1) * 64, buf ^ 1);

    const bf16_t* Kb = &Ks[buf][0];
    const bf16_t* Vb = &Vt[buf][0];

    // ---- S^T = K·Q^T : D[m=key][n=q], both q-halves share kf reads ----
    f32x4 sacc[4][2];
#pragma unroll
    for (int mt = 0; mt < 4; ++mt)
#pragma unroll
      for (int qh = 0; qh < 2; ++qh) sacc[mt][qh] = (f32x4){0.f,0.f,0.f,0.f};
#pragma unroll
    for (int ks = 0; ks < 3; ++ks) {
      bf16x8 kf[4];
#pragma unroll
      for (int mt = 0; mt < 4; ++mt)
        kf[mt] = *(const bf16x8*)&Kb[(mt * 16 + lm) * KSTR + ks * 32 + quad * 8];
      __builtin_amdgcn_s_setprio(1);
#pragma unroll
      for (int mt = 0; mt < 4; ++mt)
#pragma unroll
        for (int qh = 0; qh < 2; ++qh)
          sacc[mt][qh] = __builtin_amdgcn_mfma_f32_16x16x32_bf16(kf[mt], qf[qh][ks], sacc[mt][qh], 0, 0, 0);
      __builtin_amdgcn_s_setprio(0);
    }

    // ---- softmax (exp2, no max) + pack P; causal mask on the last TWO tiles ----
    const int kb = t * 64;
    const int keyb = kb + quad * 4;
    if (t + 2 >= ntiles) {
#pragma unroll
      for (int qh = 0; qh < 2; ++qh) {
        const int qg = qw + qh * 16 + lm;
#pragma unroll
        for (int mt = 0; mt < 4; ++mt) {
          float ps[4];
#pragma unroll
          for (int r = 0; r < 4; ++r) {
            float p = exp2_hw(sacc[mt][qh][r] * EC);
            p = (keyb + mt * 16 + r > qg) ? 0.f : p;   // causal
            ps[r] = p;
          }
          lsum[qh] += (ps[0] + ps[1]) + (ps[2] + ps[3]);
          ushort4 pk;
          pk.x = f2bf(ps[0]); pk.y = f2bf(ps[1]); pk.z = f2bf(ps[2]); pk.w = f2bf(ps[3]);
          *(ushort4*)&Ps[wave][(qh * 16 + lm) * PSTR + mt * 16 + quad * 4] = pk;
        }
      }
    } else {
#pragma unroll
      for (int qh = 0; qh < 2; ++qh) {
#pragma unroll
        for (int mt = 0; mt < 4; ++mt) {
          float ps[4];
#pragma unroll
          for (int r = 0; r < 4; ++r) ps[r] = exp2_hw(sacc[mt][qh][r] * EC);
          lsum[qh] += (ps[0] + ps[1]) + (ps[2] + ps[3]);
          ushort4 pk;
          pk.x = f2bf(ps[0]); pk.y = f2bf(ps[1]); pk.z = f2bf(ps[2]); pk.w = f2bf(ps[3]);
          *(ushort4*)&Ps[wave][(qh * 16 + lm) * PSTR + mt * 16 + quad * 4] = pk;
        }
      }
    }

    // ---- PV : O^T[d][q] += Vt·P; vf reads shared across both q-halves ----
#pragma unroll
    for (int ks = 0; ks < 2; ++ks) {
      bf16x8 vf[5], pf[2];
#pragma unroll
      for (int mt = 0; mt < 5; ++mt)
        vf[mt] = *(const bf16x8*)&Vb[(mt * 16 + lm) * VSTR + ks * 32 + quad * 8];
#pragma unroll
      for (int qh = 0; qh < 2; ++qh)
        pf[qh] = *(const bf16x8*)&Ps[wave][(qh * 16 + lm) * PSTR + ks * 32 + quad * 8];
      __builtin_amdgcn_s_setprio(1);
#pragma unroll
      for (int mt = 0; mt < 5; ++mt)
#pragma unroll
        for (int qh = 0; qh < 2; ++qh)
          oacc[mt][qh] = __builtin_amdgcn_mfma_f32_16x16x32_bf16(vf[mt], pf[qh], oacc[mt][qh], 0, 0, 0);
      __builtin_amdgcn_s_setprio(0);
    }

    // one barrier per tile: all reads of buf done; next-tile staging (into buf^1)
    // was issued a full compute-phase ago, so the implicit vmcnt(0) is cheap.
    __syncthreads();
    buf ^= 1;
  }

  // ---- epilogue: reduce l across quads, normalize, write aout (two q-rows) ----
#pragma unroll
  for (int qh = 0; qh < 2; ++qh) {
    float l = lsum[qh];
    l += __shfl_xor(l, 16);
    l += __shfl_xor(l, 32);
    const float inv = 1.f / l;
    bf16_t* base = aout + (size_t)(qw + qh * 16 + lm) * NE + h * HD + quad * 4;
#pragma unroll
    for (int mt = 0; mt < 5; ++mt) {   // d = mt*16 + quad*4 + r
      ushort4 st;
      st.x = f2bf(oacc[mt][qh][0] * inv);
      st.y = f2bf(oacc[mt][qh][1] * inv);
      st.z = f2bf(oacc[mt][qh][2] * inv);
      st.w = f2bf(oacc[mt][qh][3] * inv);
      *(ushort4*)(base + mt * 16) = st;
    }
  }
}

// ---------- launch ----------
extern "C" void kernel_launch(void* const* d_in, const int* in_sizes, int n_in,
                              void* d_out, int out_size, void* d_ws, size_t ws_size,
                              hipStream_t stream)
{
  const float* hs   = (const float*)d_in[0];  // [1, 2048, 2560] f32
  const float* wqkv = (const float*)d_in[1];  // [7680, 2560] f32
  const float* bqkv = (const float*)d_in[2];  // [7680] f32
  const float* wout = (const float*)d_in[3];  // [2560, 2560] f32
  const float* bout = (const float*)d_in[4];  // [2560] f32
  const float* cosb = (const float*)d_in[5];  // [2048, 32] f32
  const float* sinb = (const float*)d_in[6];  // [2048, 32] f32

  // workspace layout (bf16): ~105 MB total
  bf16_t* hs_bf   = (bf16_t*)d_ws;                        // 2048*2560  (dead after QKV)
  bf16_t* wqkv_bf = hs_bf   + (size_t)SEQ * NE;           // 7680*2560  (dead after QKV)
  bf16_t* wout_bf = wqkv_bf + (size_t)OP * NE;            // 2560*2560  (live until proj)
  bf16_t* qkv     = wout_bf + (size_t)NE * NE;            // 2048*7680
  bf16_t* aout    = qkv     + (size_t)SEQ * OP;           // 2048*2560
  float*  out     = (float*)d_out;                        // [2048, 2560] f32
  // overlays (stream-ordered, no overlap in live ranges):
  bf16_t* vtg     = hs_bf;          // [NH][HD][SEQ] 10.5 MB, live vtrans->attn
  float*  pbuf    = (float*)d_ws;   // [2][SEQ][NE] 41.9 MB, live proj->reduce (over vtg: ok, vtg dead)

  // 0) f32 -> bf16 conversions (single fused launch)
  constexpr int CVT_T = (SEQ * NE + OP * NE + NE * NE) / 4;   // float4 groups
  cvt3<<<CVT_T / 256, 256, 0, stream>>>(hs, wqkv, wout, hs_bf, wqkv_bf, wout_bf);

  // 1) QKV projection: qkv = hs @ Wqkv^T + b   (256x256 single-barrier pipelined, 240 blocks)
  gemm256_bt_bias<<<dim3(OP / 256, SEQ / 256), 512, 0, stream>>>(
      hs_bf, wqkv_bf, bqkv, qkv, SEQ, OP, NE);
  // 2) fused partial RoPE (in place on q,k) + V transpose -> vtg[h][d][s]
  rope_vtrans<<<8192 + 1024, 256, 0, stream>>>(qkv, cosb, sinb, vtg);
  // 3) MFMA flash attention -> aout [2048, 2560]  (512 zigzag-paired blocks, 2 blocks/CU)
  attn_mfma<<<512, 256, 0, stream>>>(qkv, vtg, aout);
  // 4) output projection, split-K x2 (640 blocks): partials, then reduce+bias
  gemm_bt_bias<float><<<dim3(NE / 128, SEQ / 128, 2), 256, 0, stream>>>(
      aout, wout_bf, nullptr, pbuf, SEQ, NE, NE, NE / 2);
  reduce2_bias<<<(SEQ * NE / 4) / 256, 256, 0, stream>>>(pbuf, bout, out);
}